// Round 2
// baseline (674.422 us; speedup 1.0000x reference)
//
#include <hip/hip_runtime.h>
#include <hip/hip_bf16.h>

typedef unsigned short u16;
typedef unsigned int u32;
typedef __attribute__((ext_vector_type(8))) short short8;
typedef __attribute__((ext_vector_type(4))) float f32x4;

#define NN 8192
#define NF 512
#define NH 256
#define SPLITZ 4

__device__ __forceinline__ float bf2f(u32 u) {
  union { u32 i; float f; } v; v.i = u << 16; return v.f;
}
__device__ __forceinline__ u16 f2bf(float f) {
  union { __hip_bfloat16 b; u16 u; } v; v.b = __float2bfloat16(f); return v.u;
}
__device__ __forceinline__ u32 pack2(float a, float b) {
  return (u32)f2bf(a) | ((u32)f2bf(b) << 16);
}

// ---- adj fp32 -> bf16, fused row & col sums. grid (4, 64), 256 thr ----
__global__ __launch_bounds__(256) void conv_adj_k(const float* __restrict__ adj,
                                                  u16* __restrict__ adjb,
                                                  float* __restrict__ rowsum,
                                                  float* __restrict__ colsum) {
  __shared__ float red[4][128];
  const int t = threadIdx.x;
  const int w = t >> 6, lane = t & 63;
  const int c0 = blockIdx.x * 2048 + t * 8;
  const int r0 = blockIdx.y * 128;
  float cp[8] = {0.f, 0.f, 0.f, 0.f, 0.f, 0.f, 0.f, 0.f};
  for (int r = 0; r < 128; ++r) {
    const size_t base = (size_t)(r0 + r) * NN + c0;
    float4 v0 = *(const float4*)(adj + base);
    float4 v1 = *(const float4*)(adj + base + 4);
    uint4 pk;
    pk.x = pack2(v0.x, v0.y); pk.y = pack2(v0.z, v0.w);
    pk.z = pack2(v1.x, v1.y); pk.w = pack2(v1.z, v1.w);
    *(uint4*)(adjb + base) = pk;
    cp[0] += v0.x; cp[1] += v0.y; cp[2] += v0.z; cp[3] += v0.w;
    cp[4] += v1.x; cp[5] += v1.y; cp[6] += v1.z; cp[7] += v1.w;
    float rs = (v0.x + v0.y) + (v0.z + v0.w) + ((v1.x + v1.y) + (v1.z + v1.w));
#pragma unroll
    for (int off = 32; off > 0; off >>= 1) rs += __shfl_down(rs, off, 64);
    if (lane == 0) red[w][r] = rs;
  }
  __syncthreads();
  if (t < 128)
    atomicAdd(&rowsum[r0 + t], red[0][t] + red[1][t] + red[2][t] + red[3][t]);
#pragma unroll
  for (int j = 0; j < 8; ++j) atomicAdd(&colsum[c0 + j], cp[j]);
}

// ---- sums -> ^-0.5 with 0-guard (rowsum/colsum contiguous; drow/dcol contiguous) ----
__global__ void finalize_k(const float* __restrict__ sums, float* __restrict__ d, int n) {
  const int i = blockIdx.x * blockDim.x + threadIdx.x;
  if (i < n) {
    const float s = sums[i];
    d[i] = (s > 0.f) ? rsqrtf(s) : 0.f;
  }
}

// ---- x fp32 -> bf16, 8 elems/thread ----
__global__ __launch_bounds__(256) void convx_k(const float* __restrict__ x,
                                               u16* __restrict__ xb) {
  const size_t i = ((size_t)blockIdx.x * 256 + threadIdx.x) * 8;
  float4 v0 = *(const float4*)(x + i);
  float4 v1 = *(const float4*)(x + i + 4);
  uint4 pk;
  pk.x = pack2(v0.x, v0.y); pk.y = pack2(v0.z, v0.w);
  pk.z = pack2(v1.x, v1.y); pk.w = pack2(v1.z, v1.w);
  *(uint4*)(xb + i) = pk;
}

// ---- W1 (512x256 fp32) -> W1t (256x512 bf16) transpose ----
__global__ __launch_bounds__(256) void convw1_k(const float* __restrict__ in,
                                                u16* __restrict__ out) {
  __shared__ float tile[32][33];
  const int tx = threadIdx.x & 31, ty = threadIdx.x >> 5;
  const int c0 = blockIdx.x * 32;  // over NH
  const int r0 = blockIdx.y * 32;  // over NF
#pragma unroll
  for (int d = 0; d < 32; d += 8)
    tile[ty + d][tx] = in[(size_t)(r0 + ty + d) * NH + c0 + tx];
  __syncthreads();
#pragma unroll
  for (int d = 0; d < 32; d += 8)
    out[(size_t)(c0 + ty + d) * NF + r0 + tx] = f2bf(tile[tx][ty + d]);
}

// ---- MFMA GEMM, 128x128 tile, BK=32, double-buffered global_load_lds ----
__device__ __forceinline__ void stage128(const u16* __restrict__ A, int lda,
                                         const u16* __restrict__ Bt, int ldb,
                                         int m0, int n0, int kk,
                                         u16* as_, u16* bs_, int tid) {
#pragma unroll
  for (int h = 0; h < 2; ++h) {
    const int slot = tid + h * 256;
    const int row = slot >> 2, kc = slot & 3;
    const u16* srcA = A + (size_t)(m0 + row) * lda + kk + kc * 8;
    __builtin_amdgcn_global_load_lds((const __attribute__((address_space(1))) void*)srcA,
                                     (__attribute__((address_space(3))) void*)(as_ + slot * 8),
                                     16, 0, 0);
    const u16* srcB = Bt + (size_t)(n0 + row) * ldb + kk + kc * 8;
    __builtin_amdgcn_global_load_lds((const __attribute__((address_space(1))) void*)srcB,
                                     (__attribute__((address_space(3))) void*)(bs_ + slot * 8),
                                     16, 0, 0);
  }
}

__global__ __launch_bounds__(256) void gemm_k(const u16* __restrict__ A, int lda,
                                              const u16* __restrict__ Bt, int ldb,
                                              int kChunk, float* __restrict__ out) {
  __shared__ __align__(16) u16 As[2][128 * 32];
  __shared__ __align__(16) u16 Bs[2][128 * 32];
  const int tid = threadIdx.x;
  const int w = tid >> 6, lane = tid & 63;
  const int lq = lane >> 4, lr = lane & 15;
  const int wr = (w >> 1) * 64, wc = (w & 1) * 64;
  const int m0 = blockIdx.x * 128;
  const int n0 = blockIdx.y * 128;
  const int kk0 = blockIdx.z * kChunk;
  const int nk = kChunk >> 5;

  f32x4 acc[4][4] = {};

  stage128(A, lda, Bt, ldb, m0, n0, kk0, As[0], Bs[0], tid);
  for (int kt = 0; kt < nk; ++kt) {
    const int cur = kt & 1;
    __syncthreads();  // drains vmcnt: buf 'cur' ready; buf '!cur' free
    if (kt + 1 < nk)
      stage128(A, lda, Bt, ldb, m0, n0, kk0 + ((kt + 1) << 5), As[cur ^ 1], Bs[cur ^ 1], tid);
    short8 a[4], b[4];
#pragma unroll
    for (int i = 0; i < 4; ++i)
      a[i] = *(const short8*)(As[cur] + (wr + i * 16 + lr) * 32 + lq * 8);
#pragma unroll
    for (int i = 0; i < 4; ++i)
      b[i] = *(const short8*)(Bs[cur] + (wc + i * 16 + lr) * 32 + lq * 8);
#pragma unroll
    for (int i = 0; i < 4; ++i)
#pragma unroll
      for (int j = 0; j < 4; ++j)
        acc[i][j] = __builtin_amdgcn_mfma_f32_16x16x32_bf16(a[i], b[j], acc[i][j], 0, 0, 0);
  }

  float* o = out + (size_t)blockIdx.z * ((size_t)NN * NH);
  // C/D layout: col = lane&15, row = (lane>>4)*4 + reg
#pragma unroll
  for (int i = 0; i < 4; ++i)
#pragma unroll
    for (int j = 0; j < 4; ++j) {
      const int gn = n0 + wc + j * 16 + lr;
      const int gm0 = m0 + wr + i * 16 + lq * 4;
#pragma unroll
      for (int r = 0; r < 4; ++r)
        o[(size_t)(gm0 + r) * NH + gn] = acc[i][j][r];
    }
}

// ---- B1t = (d_col .* P)^T as bf16 ----
__global__ __launch_bounds__(256) void t1_k(const float* __restrict__ P,
                                            const float* __restrict__ dcol,
                                            u16* __restrict__ B1t) {
  __shared__ float tile[32][33];
  const int tx = threadIdx.x & 31, ty = threadIdx.x >> 5;
  const int c0 = blockIdx.x * 32;  // over NH
  const int r0 = blockIdx.y * 32;  // over NN
#pragma unroll
  for (int d = 0; d < 32; d += 8) {
    const int rr = r0 + ty + d;
    tile[ty + d][tx] = dcol[rr] * P[(size_t)rr * NH + c0 + tx];
  }
  __syncthreads();
#pragma unroll
  for (int d = 0; d < 32; d += 8)
    B1t[(size_t)(c0 + ty + d) * NN + r0 + tx] = f2bf(tile[tx][ty + d]);
}

// ---- reduce 4 partials -> Q1 (fp32) and B2t = (d_col .* Q1)^T (bf16) ----
__global__ __launch_bounds__(256) void r2_k(const float* __restrict__ Qp,
                                            const float* __restrict__ drow,
                                            const float* __restrict__ dcol,
                                            float* __restrict__ Q1,
                                            u16* __restrict__ B2t) {
  __shared__ float tile[32][33];
  const int tx = threadIdx.x & 31, ty = threadIdx.x >> 5;
  const int c0 = blockIdx.x * 32;
  const int r0 = blockIdx.y * 32;
  const size_t sl = (size_t)NN * NH;
#pragma unroll
  for (int d = 0; d < 32; d += 8) {
    const int rr = r0 + ty + d;
    const size_t idx = (size_t)rr * NH + c0 + tx;
    const float s = (Qp[idx] + Qp[idx + sl]) + (Qp[idx + 2 * sl] + Qp[idx + 3 * sl]);
    const float q = drow[rr] * s;
    Q1[idx] = q;
    tile[ty + d][tx] = dcol[rr] * q;
  }
  __syncthreads();
#pragma unroll
  for (int d = 0; d < 32; d += 8)
    B2t[(size_t)(c0 + ty + d) * NN + r0 + tx] = f2bf(tile[tx][ty + d]);
}

// ---- h = relu(0.5P - 0.5Q1 - d_row .* sum(Hp)) -> bf16 ----
__global__ __launch_bounds__(256) void r3_k(const float* __restrict__ Hp,
                                            const float* __restrict__ P,
                                            const float* __restrict__ Q1,
                                            const float* __restrict__ drow,
                                            u16* __restrict__ Hb) {
  const size_t i = ((size_t)blockIdx.x * 256 + threadIdx.x) * 4;
  const int row = (int)(i >> 8);
  const size_t sl = (size_t)NN * NH;
  float4 a = *(const float4*)(Hp + i);
  float4 b = *(const float4*)(Hp + i + sl);
  float4 c = *(const float4*)(Hp + i + 2 * sl);
  float4 d = *(const float4*)(Hp + i + 3 * sl);
  float4 p = *(const float4*)(P + i);
  float4 q = *(const float4*)(Q1 + i);
  const float dr = drow[row];
  const float h0 = fmaxf(0.5f * p.x - 0.5f * q.x - dr * ((a.x + b.x) + (c.x + d.x)), 0.f);
  const float h1 = fmaxf(0.5f * p.y - 0.5f * q.y - dr * ((a.y + b.y) + (c.y + d.y)), 0.f);
  const float h2 = fmaxf(0.5f * p.z - 0.5f * q.z - dr * ((a.z + b.z) + (c.z + d.z)), 0.f);
  const float h3 = fmaxf(0.5f * p.w - 0.5f * q.w - dr * ((a.w + b.w) + (c.w + d.w)), 0.f);
  uint2 pk;
  pk.x = pack2(h0, h1);
  pk.y = pack2(h2, h3);
  *(uint2*)(Hb + i) = pk;
}

// ---- R = h@W2 (one wave per row); B3 = d_col .* R (fp32) ----
__global__ __launch_bounds__(256) void r_k(const u16* __restrict__ H,
                                           const float* __restrict__ W2,
                                           const float* __restrict__ dcol,
                                           float* __restrict__ R, float* __restrict__ B3) {
  const int w = threadIdx.x >> 6, lane = threadIdx.x & 63;
  const int i = blockIdx.x * 4 + w;
  uint2 hv = *(const uint2*)(H + (size_t)i * NH + lane * 4);
  float4 w01 = *(const float4*)(W2 + lane * 8);
  float4 w23 = *(const float4*)(W2 + lane * 8 + 4);
  const float h0 = bf2f(hv.x & 0xffffu), h1 = bf2f(hv.x >> 16);
  const float h2 = bf2f(hv.y & 0xffffu), h3 = bf2f(hv.y >> 16);
  float a0 = h0 * w01.x + h1 * w01.z + h2 * w23.x + h3 * w23.z;
  float a1 = h0 * w01.y + h1 * w01.w + h2 * w23.y + h3 * w23.w;
#pragma unroll
  for (int off = 32; off > 0; off >>= 1) {
    a0 += __shfl_down(a0, off, 64);
    a1 += __shfl_down(a1, off, 64);
  }
  if (lane == 0) {
    R[i * 2] = a0;
    R[i * 2 + 1] = a1;
    const float dc = dcol[i];
    B3[i * 2] = dc * a0;
    B3[i * 2 + 1] = dc * a1;
  }
}

// ---- row GEMV over adjb (bf16) with 2-wide fp32 B; fused epilogues ----
__global__ __launch_bounds__(256) void gemv_k(
    const u16* __restrict__ adjb, const float* __restrict__ B,
    const float* __restrict__ drow, const float* __restrict__ dcol,
    const float* __restrict__ Rin, const float* __restrict__ S1in,
    const float* __restrict__ b2, float* __restrict__ S1out,
    float* __restrict__ B4, float* __restrict__ outp, int mode) {
  const int i = blockIdx.x;
  const int t = threadIdx.x;
  float a0 = 0.f, a1 = 0.f;
#pragma unroll
  for (int c = 0; c < 4; ++c) {
    const int col = c * 2048 + t * 8;
    uint4 av = *(const uint4*)(adjb + (size_t)i * NN + col);
    const u32* aw = (const u32*)&av;
    float bv[16];
    *(float4*)(bv) = *(const float4*)(B + col * 2);
    *(float4*)(bv + 4) = *(const float4*)(B + col * 2 + 4);
    *(float4*)(bv + 8) = *(const float4*)(B + col * 2 + 8);
    *(float4*)(bv + 12) = *(const float4*)(B + col * 2 + 12);
#pragma unroll
    for (int j = 0; j < 8; ++j) {
      const u32 a = aw[j >> 1];
      const float aval = bf2f((j & 1) ? (a >> 16) : (a & 0xffffu));
      a0 += aval * bv[2 * j];
      a1 += aval * bv[2 * j + 1];
    }
  }
#pragma unroll
  for (int off = 32; off > 0; off >>= 1) {
    a0 += __shfl_down(a0, off, 64);
    a1 += __shfl_down(a1, off, 64);
  }
  __shared__ float red[8];
  const int w = t >> 6, lane = t & 63;
  if (lane == 0) { red[w] = a0; red[4 + w] = a1; }
  __syncthreads();
  if (t == 0) {
    float s0 = (red[0] + red[1]) + (red[2] + red[3]);
    float s1 = (red[4] + red[5]) + (red[6] + red[7]);
    const float dr = drow[i];
    s0 *= dr; s1 *= dr;
    if (mode == 0) {  // S1 = d_row .* (adj@B3); B4 = d_col .* S1
      S1out[i * 2] = s0;
      S1out[i * 2 + 1] = s1;
      const float dc = dcol[i];
      B4[i * 2] = dc * s0;
      B4[i * 2 + 1] = dc * s1;
    } else {  // logits = 0.5R - 0.5S1 - S2 + b2; log_softmax
      const float l0 = 0.5f * Rin[i * 2] - 0.5f * S1in[i * 2] - s0 + b2[0];
      const float l1 = 0.5f * Rin[i * 2 + 1] - 0.5f * S1in[i * 2 + 1] - s1 + b2[1];
      const float m = fmaxf(l0, l1);
      const float lse = m + logf(__expf(l0 - m) + __expf(l1 - m));
      outp[i * 2] = l0 - lse;
      outp[i * 2 + 1] = l1 - lse;
    }
  }
}

extern "C" void kernel_launch(void* const* d_in, const int* in_sizes, int n_in,
                              void* d_out, int out_size, void* d_ws, size_t ws_size,
                              hipStream_t stream) {
  (void)in_sizes; (void)n_in; (void)out_size; (void)ws_size;
  const float* x   = (const float*)d_in[0];
  const float* adj = (const float*)d_in[1];
  const float* W1  = (const float*)d_in[2];
  const float* W2  = (const float*)d_in[3];
  const float* b2  = (const float*)d_in[4];
  float* outp = (float*)d_out;

  char* ws = (char*)d_ws;
  size_t off = 0;
  auto alloc = [&](size_t bytes) -> char* {
    char* p = ws + off;
    off += (bytes + 255) & ~(size_t)255;
    return p;
  };
  u16* adjb  = (u16*)alloc((size_t)NN * NN * 2);          // 134 MB
  u16* xb    = (u16*)alloc((size_t)NN * NF * 2);          // 8.4 MB
  u16* W1t   = (u16*)alloc((size_t)NH * NF * 2);          // 0.26 MB
  float* rowsum = (float*)alloc((size_t)NN * 4);
  float* colsum = (float*)alloc((size_t)NN * 4);          // contiguous with rowsum
  float* drow   = (float*)alloc((size_t)NN * 4);
  float* dcol   = (float*)alloc((size_t)NN * 4);          // contiguous with drow
  float* P   = (float*)alloc((size_t)NN * NH * 4);        // 8.4 MB
  u16* B1t   = (u16*)alloc((size_t)NH * NN * 2);          // 4.2 MB
  float* Qp  = (float*)alloc((size_t)SPLITZ * NN * NH * 4);  // 33.6 MB (reused as Hp)
  float* Q1  = (float*)alloc((size_t)NN * NH * 4);        // 8.4 MB
  u16* B2t   = (u16*)alloc((size_t)NH * NN * 2);          // 4.2 MB
  u16* Hb    = (u16*)alloc((size_t)NN * NH * 2);          // 4.2 MB
  float* R   = (float*)alloc((size_t)NN * 2 * 4);
  float* B3  = (float*)alloc((size_t)NN * 2 * 4);
  float* S1  = (float*)alloc((size_t)NN * 2 * 4);
  float* B4  = (float*)alloc((size_t)NN * 2 * 4);
  float* Hp  = Qp;  // alias: Qp consumed by r2_k before gemm3 writes Hp

  (void)hipMemsetAsync(rowsum, 0, (size_t)2 * NN * 4, stream);  // rowsum+colsum

  conv_adj_k<<<dim3(4, 64), 256, 0, stream>>>(adj, adjb, rowsum, colsum);
  finalize_k<<<64, 256, 0, stream>>>(rowsum, drow, 2 * NN);
  convx_k<<<2048, 256, 0, stream>>>(x, xb);
  convw1_k<<<dim3(8, 16), 256, 0, stream>>>(W1, W1t);

  // P = x@W1 (fp32 out)
  gemm_k<<<dim3(64, 2, 1), 256, 0, stream>>>(xb, NF, W1t, NF, NF, P);
  t1_k<<<dim3(8, 256), 256, 0, stream>>>(P, dcol, B1t);

  // Qp[z] = partial adj@B1
  gemm_k<<<dim3(64, 2, SPLITZ), 256, 0, stream>>>(adjb, NN, B1t, NN, NN / SPLITZ, Qp);
  r2_k<<<dim3(8, 256), 256, 0, stream>>>(Qp, drow, dcol, Q1, B2t);

  // Hp[z] = partial adj@B2
  gemm_k<<<dim3(64, 2, SPLITZ), 256, 0, stream>>>(adjb, NN, B2t, NN, NN / SPLITZ, Hp);
  r3_k<<<2048, 256, 0, stream>>>(Hp, P, Q1, drow, Hb);

  r_k<<<NN / 4, 256, 0, stream>>>(Hb, W2, dcol, R, B3);
  gemv_k<<<NN, 256, 0, stream>>>(adjb, B3, drow, dcol, nullptr, nullptr, nullptr, S1, B4, nullptr, 0);
  gemv_k<<<NN, 256, 0, stream>>>(adjb, B4, drow, dcol, R, S1, b2, nullptr, nullptr, outp, 1);
}

// Round 3
// 664.096 us; speedup vs baseline: 1.0155x; 1.0155x over previous
//
#include <hip/hip_runtime.h>
#include <hip/hip_bf16.h>

typedef unsigned short u16;
typedef unsigned int u32;
typedef __attribute__((ext_vector_type(8))) short short8;
typedef __attribute__((ext_vector_type(4))) float f32x4;

#define NN 8192
#define NF 512
#define NH 256
#define SPLITZ 4
#define RB 256          // row-blocks in conv_adj (32 rows each)

__device__ __forceinline__ float bf2f(u32 u) {
  union { u32 i; float f; } v; v.i = u << 16; return v.f;
}
__device__ __forceinline__ u16 f2bf(float f) {
  union { __hip_bfloat16 b; u16 u; } v; v.b = __float2bfloat16(f); return v.u;
}
__device__ __forceinline__ u32 pack2(float a, float b) {
  return (u32)f2bf(a) | ((u32)f2bf(b) << 16);
}

// ---- adj fp32 -> bf16, fused row & col partial sums (atomic-free) ----
// grid (4, RB), 256 thr. Block (s, rb): cols s*2048 + t*8, rows rb*32..+32.
__global__ __launch_bounds__(256) void conv_adj_k(const float* __restrict__ adj,
                                                  u16* __restrict__ adjb,
                                                  float* __restrict__ rowsum_part,
                                                  float* __restrict__ colsum_part) {
  __shared__ float red[4][32];
  const int t = threadIdx.x;
  const int w = t >> 6, lane = t & 63;
  const int s = blockIdx.x;
  const int c0 = s * 2048 + t * 8;
  const int r0 = blockIdx.y * 32;
  float cp[8] = {0.f, 0.f, 0.f, 0.f, 0.f, 0.f, 0.f, 0.f};
  for (int r = 0; r < 32; ++r) {
    const size_t base = (size_t)(r0 + r) * NN + c0;
    float4 v0 = *(const float4*)(adj + base);
    float4 v1 = *(const float4*)(adj + base + 4);
    uint4 pk;
    pk.x = pack2(v0.x, v0.y); pk.y = pack2(v0.z, v0.w);
    pk.z = pack2(v1.x, v1.y); pk.w = pack2(v1.z, v1.w);
    *(uint4*)(adjb + base) = pk;
    cp[0] += v0.x; cp[1] += v0.y; cp[2] += v0.z; cp[3] += v0.w;
    cp[4] += v1.x; cp[5] += v1.y; cp[6] += v1.z; cp[7] += v1.w;
    float rs = (v0.x + v0.y) + (v0.z + v0.w) + ((v1.x + v1.y) + (v1.z + v1.w));
#pragma unroll
    for (int off = 32; off > 0; off >>= 1) rs += __shfl_down(rs, off, 64);
    if (lane == 0) red[w][r] = rs;
  }
  __syncthreads();
  if (t < 32)
    rowsum_part[(size_t)s * NN + r0 + t] =
        (red[0][t] + red[1][t]) + (red[2][t] + red[3][t]);
  float* cdst = colsum_part + (size_t)blockIdx.y * NN + c0;
  *(float4*)cdst = make_float4(cp[0], cp[1], cp[2], cp[3]);
  *(float4*)(cdst + 4) = make_float4(cp[4], cp[5], cp[6], cp[7]);
}

// ---- reduce partials -> drow/dcol = sums^-0.5 with 0-guard ----
__global__ __launch_bounds__(256) void reduce_sums_k(const float* __restrict__ rowp,
                                                     const float* __restrict__ colp,
                                                     float* __restrict__ drow,
                                                     float* __restrict__ dcol) {
  const int i = blockIdx.x * 256 + threadIdx.x;
  const float rs = (rowp[i] + rowp[NN + i]) + (rowp[2 * NN + i] + rowp[3 * NN + i]);
  drow[i] = (rs > 0.f) ? rsqrtf(rs) : 0.f;
  float cs = 0.f;
#pragma unroll 8
  for (int rb = 0; rb < RB; ++rb) cs += colp[(size_t)rb * NN + i];
  dcol[i] = (cs > 0.f) ? rsqrtf(cs) : 0.f;
}

// ---- x fp32 -> bf16, 8 elems/thread ----
__global__ __launch_bounds__(256) void convx_k(const float* __restrict__ x,
                                               u16* __restrict__ xb) {
  const size_t i = ((size_t)blockIdx.x * 256 + threadIdx.x) * 8;
  float4 v0 = *(const float4*)(x + i);
  float4 v1 = *(const float4*)(x + i + 4);
  uint4 pk;
  pk.x = pack2(v0.x, v0.y); pk.y = pack2(v0.z, v0.w);
  pk.z = pack2(v1.x, v1.y); pk.w = pack2(v1.z, v1.w);
  *(uint4*)(xb + i) = pk;
}

// ---- W1 (512x256 fp32) -> W1t (256x512 bf16) transpose ----
__global__ __launch_bounds__(256) void convw1_k(const float* __restrict__ in,
                                                u16* __restrict__ out) {
  __shared__ float tile[32][33];
  const int tx = threadIdx.x & 31, ty = threadIdx.x >> 5;
  const int c0 = blockIdx.x * 32;  // over NH
  const int r0 = blockIdx.y * 32;  // over NF
#pragma unroll
  for (int d = 0; d < 32; d += 8)
    tile[ty + d][tx] = in[(size_t)(r0 + ty + d) * NH + c0 + tx];
  __syncthreads();
#pragma unroll
  for (int d = 0; d < 32; d += 8)
    out[(size_t)(c0 + ty + d) * NF + r0 + tx] = f2bf(tile[tx][ty + d]);
}

// ---- MFMA GEMM, 128x128 tile, BK=32, double-buffered global_load_lds ----
__device__ __forceinline__ void stage128(const u16* __restrict__ A, int lda,
                                         const u16* __restrict__ Bt, int ldb,
                                         int m0, int n0, int kk,
                                         u16* as_, u16* bs_, int tid) {
#pragma unroll
  for (int h = 0; h < 2; ++h) {
    const int slot = tid + h * 256;
    const int row = slot >> 2, kc = slot & 3;
    const u16* srcA = A + (size_t)(m0 + row) * lda + kk + kc * 8;
    __builtin_amdgcn_global_load_lds((const __attribute__((address_space(1))) void*)srcA,
                                     (__attribute__((address_space(3))) void*)(as_ + slot * 8),
                                     16, 0, 0);
    const u16* srcB = Bt + (size_t)(n0 + row) * ldb + kk + kc * 8;
    __builtin_amdgcn_global_load_lds((const __attribute__((address_space(1))) void*)srcB,
                                     (__attribute__((address_space(3))) void*)(bs_ + slot * 8),
                                     16, 0, 0);
  }
}

// grid (n-tiles, m-tiles, z); n fastest so the two blocks sharing an A-stripe
// are dispatch-adjacent (second adjb stripe read hits LLC warm).
__global__ __launch_bounds__(256) void gemm_k(const u16* __restrict__ A, int lda,
                                              const u16* __restrict__ Bt, int ldb,
                                              int kChunk, float* __restrict__ out) {
  __shared__ __align__(16) u16 As[2][128 * 32];
  __shared__ __align__(16) u16 Bs[2][128 * 32];
  const int tid = threadIdx.x;
  const int w = tid >> 6, lane = tid & 63;
  const int lq = lane >> 4, lr = lane & 15;
  const int wr = (w >> 1) * 64, wc = (w & 1) * 64;
  const int n0 = blockIdx.x * 128;
  const int m0 = blockIdx.y * 128;
  const int kk0 = blockIdx.z * kChunk;
  const int nk = kChunk >> 5;

  f32x4 acc[4][4] = {};

  stage128(A, lda, Bt, ldb, m0, n0, kk0, As[0], Bs[0], tid);
  for (int kt = 0; kt < nk; ++kt) {
    const int cur = kt & 1;
    __syncthreads();  // drains vmcnt: buf 'cur' ready; buf '!cur' free
    if (kt + 1 < nk)
      stage128(A, lda, Bt, ldb, m0, n0, kk0 + ((kt + 1) << 5), As[cur ^ 1], Bs[cur ^ 1], tid);
    short8 a[4], b[4];
#pragma unroll
    for (int i = 0; i < 4; ++i)
      a[i] = *(const short8*)(As[cur] + (wr + i * 16 + lr) * 32 + lq * 8);
#pragma unroll
    for (int i = 0; i < 4; ++i)
      b[i] = *(const short8*)(Bs[cur] + (wc + i * 16 + lr) * 32 + lq * 8);
#pragma unroll
    for (int i = 0; i < 4; ++i)
#pragma unroll
      for (int j = 0; j < 4; ++j)
        acc[i][j] = __builtin_amdgcn_mfma_f32_16x16x32_bf16(a[i], b[j], acc[i][j], 0, 0, 0);
  }

  float* o = out + (size_t)blockIdx.z * ((size_t)NN * NH);
  // C/D layout: col = lane&15, row = (lane>>4)*4 + reg
#pragma unroll
  for (int i = 0; i < 4; ++i)
#pragma unroll
    for (int j = 0; j < 4; ++j) {
      const int gn = n0 + wc + j * 16 + lr;
      const int gm0 = m0 + wr + i * 16 + lq * 4;
#pragma unroll
      for (int r = 0; r < 4; ++r)
        o[(size_t)(gm0 + r) * NH + gn] = acc[i][j][r];
    }
}

// ---- B1t = (d_col .* P)^T as bf16 ----
__global__ __launch_bounds__(256) void t1_k(const float* __restrict__ P,
                                            const float* __restrict__ dcol,
                                            u16* __restrict__ B1t) {
  __shared__ float tile[32][33];
  const int tx = threadIdx.x & 31, ty = threadIdx.x >> 5;
  const int c0 = blockIdx.x * 32;  // over NH
  const int r0 = blockIdx.y * 32;  // over NN
#pragma unroll
  for (int d = 0; d < 32; d += 8) {
    const int rr = r0 + ty + d;
    tile[ty + d][tx] = dcol[rr] * P[(size_t)rr * NH + c0 + tx];
  }
  __syncthreads();
#pragma unroll
  for (int d = 0; d < 32; d += 8)
    B1t[(size_t)(c0 + ty + d) * NN + r0 + tx] = f2bf(tile[tx][ty + d]);
}

// ---- reduce 4 partials -> Q1 (fp32) and B2t = (d_col .* Q1)^T (bf16) ----
__global__ __launch_bounds__(256) void r2_k(const float* __restrict__ Qp,
                                            const float* __restrict__ drow,
                                            const float* __restrict__ dcol,
                                            float* __restrict__ Q1,
                                            u16* __restrict__ B2t) {
  __shared__ float tile[32][33];
  const int tx = threadIdx.x & 31, ty = threadIdx.x >> 5;
  const int c0 = blockIdx.x * 32;
  const int r0 = blockIdx.y * 32;
  const size_t sl = (size_t)NN * NH;
#pragma unroll
  for (int d = 0; d < 32; d += 8) {
    const int rr = r0 + ty + d;
    const size_t idx = (size_t)rr * NH + c0 + tx;
    const float s = (Qp[idx] + Qp[idx + sl]) + (Qp[idx + 2 * sl] + Qp[idx + 3 * sl]);
    const float q = drow[rr] * s;
    Q1[idx] = q;
    tile[ty + d][tx] = dcol[rr] * q;
  }
  __syncthreads();
#pragma unroll
  for (int d = 0; d < 32; d += 8)
    B2t[(size_t)(c0 + ty + d) * NN + r0 + tx] = f2bf(tile[tx][ty + d]);
}

// ---- h = relu(0.5P - 0.5Q1 - d_row .* sum(Hp)) -> bf16 ----
__global__ __launch_bounds__(256) void r3_k(const float* __restrict__ Hp,
                                            const float* __restrict__ P,
                                            const float* __restrict__ Q1,
                                            const float* __restrict__ drow,
                                            u16* __restrict__ Hb) {
  const size_t i = ((size_t)blockIdx.x * 256 + threadIdx.x) * 4;
  const int row = (int)(i >> 8);
  const size_t sl = (size_t)NN * NH;
  float4 a = *(const float4*)(Hp + i);
  float4 b = *(const float4*)(Hp + i + sl);
  float4 c = *(const float4*)(Hp + i + 2 * sl);
  float4 d = *(const float4*)(Hp + i + 3 * sl);
  float4 p = *(const float4*)(P + i);
  float4 q = *(const float4*)(Q1 + i);
  const float dr = drow[row];
  const float h0 = fmaxf(0.5f * p.x - 0.5f * q.x - dr * ((a.x + b.x) + (c.x + d.x)), 0.f);
  const float h1 = fmaxf(0.5f * p.y - 0.5f * q.y - dr * ((a.y + b.y) + (c.y + d.y)), 0.f);
  const float h2 = fmaxf(0.5f * p.z - 0.5f * q.z - dr * ((a.z + b.z) + (c.z + d.z)), 0.f);
  const float h3 = fmaxf(0.5f * p.w - 0.5f * q.w - dr * ((a.w + b.w) + (c.w + d.w)), 0.f);
  uint2 pk;
  pk.x = pack2(h0, h1);
  pk.y = pack2(h2, h3);
  *(uint2*)(Hb + i) = pk;
}

// ---- R = h@W2 (one wave per row); B3 = d_col .* R (fp32) ----
__global__ __launch_bounds__(256) void r_k(const u16* __restrict__ H,
                                           const float* __restrict__ W2,
                                           const float* __restrict__ dcol,
                                           float* __restrict__ R, float* __restrict__ B3) {
  const int w = threadIdx.x >> 6, lane = threadIdx.x & 63;
  const int i = blockIdx.x * 4 + w;
  uint2 hv = *(const uint2*)(H + (size_t)i * NH + lane * 4);
  float4 w01 = *(const float4*)(W2 + lane * 8);
  float4 w23 = *(const float4*)(W2 + lane * 8 + 4);
  const float h0 = bf2f(hv.x & 0xffffu), h1 = bf2f(hv.x >> 16);
  const float h2 = bf2f(hv.y & 0xffffu), h3 = bf2f(hv.y >> 16);
  float a0 = h0 * w01.x + h1 * w01.z + h2 * w23.x + h3 * w23.z;
  float a1 = h0 * w01.y + h1 * w01.w + h2 * w23.y + h3 * w23.w;
#pragma unroll
  for (int off = 32; off > 0; off >>= 1) {
    a0 += __shfl_down(a0, off, 64);
    a1 += __shfl_down(a1, off, 64);
  }
  if (lane == 0) {
    R[i * 2] = a0;
    R[i * 2 + 1] = a1;
    const float dc = dcol[i];
    B3[i * 2] = dc * a0;
    B3[i * 2 + 1] = dc * a1;
  }
}

// ---- row GEMV over adjb (bf16) with 2-wide fp32 B; fused epilogues ----
__global__ __launch_bounds__(256) void gemv_k(
    const u16* __restrict__ adjb, const float* __restrict__ B,
    const float* __restrict__ drow, const float* __restrict__ dcol,
    const float* __restrict__ Rin, const float* __restrict__ S1in,
    const float* __restrict__ b2, float* __restrict__ S1out,
    float* __restrict__ B4, float* __restrict__ outp, int mode) {
  const int i = blockIdx.x;
  const int t = threadIdx.x;
  float a0 = 0.f, a1 = 0.f;
#pragma unroll
  for (int c = 0; c < 4; ++c) {
    const int col = c * 2048 + t * 8;
    uint4 av = *(const uint4*)(adjb + (size_t)i * NN + col);
    const u32* aw = (const u32*)&av;
    float bv[16];
    *(float4*)(bv) = *(const float4*)(B + col * 2);
    *(float4*)(bv + 4) = *(const float4*)(B + col * 2 + 4);
    *(float4*)(bv + 8) = *(const float4*)(B + col * 2 + 8);
    *(float4*)(bv + 12) = *(const float4*)(B + col * 2 + 12);
#pragma unroll
    for (int j = 0; j < 8; ++j) {
      const u32 a = aw[j >> 1];
      const float aval = bf2f((j & 1) ? (a >> 16) : (a & 0xffffu));
      a0 += aval * bv[2 * j];
      a1 += aval * bv[2 * j + 1];
    }
  }
#pragma unroll
  for (int off = 32; off > 0; off >>= 1) {
    a0 += __shfl_down(a0, off, 64);
    a1 += __shfl_down(a1, off, 64);
  }
  __shared__ float red[8];
  const int w = t >> 6, lane = t & 63;
  if (lane == 0) { red[w] = a0; red[4 + w] = a1; }
  __syncthreads();
  if (t == 0) {
    float s0 = (red[0] + red[1]) + (red[2] + red[3]);
    float s1 = (red[4] + red[5]) + (red[6] + red[7]);
    const float dr = drow[i];
    s0 *= dr; s1 *= dr;
    if (mode == 0) {  // S1 = d_row .* (adj@B3); B4 = d_col .* S1
      S1out[i * 2] = s0;
      S1out[i * 2 + 1] = s1;
      const float dc = dcol[i];
      B4[i * 2] = dc * s0;
      B4[i * 2 + 1] = dc * s1;
    } else {  // logits = 0.5R - 0.5S1 - S2 + b2; log_softmax
      const float l0 = 0.5f * Rin[i * 2] - 0.5f * S1in[i * 2] - s0 + b2[0];
      const float l1 = 0.5f * Rin[i * 2 + 1] - 0.5f * S1in[i * 2 + 1] - s1 + b2[1];
      const float m = fmaxf(l0, l1);
      const float lse = m + logf(__expf(l0 - m) + __expf(l1 - m));
      outp[i * 2] = l0 - lse;
      outp[i * 2 + 1] = l1 - lse;
    }
  }
}

extern "C" void kernel_launch(void* const* d_in, const int* in_sizes, int n_in,
                              void* d_out, int out_size, void* d_ws, size_t ws_size,
                              hipStream_t stream) {
  (void)in_sizes; (void)n_in; (void)out_size; (void)ws_size;
  const float* x   = (const float*)d_in[0];
  const float* adj = (const float*)d_in[1];
  const float* W1  = (const float*)d_in[2];
  const float* W2  = (const float*)d_in[3];
  const float* b2  = (const float*)d_in[4];
  float* outp = (float*)d_out;

  char* ws = (char*)d_ws;
  size_t off = 0;
  auto alloc = [&](size_t bytes) -> char* {
    char* p = ws + off;
    off += (bytes + 255) & ~(size_t)255;
    return p;
  };
  u16* adjb  = (u16*)alloc((size_t)NN * NN * 2);             // 134 MB
  u16* xb    = (u16*)alloc((size_t)NN * NF * 2);             // 8.4 MB
  u16* W1t   = (u16*)alloc((size_t)NH * NF * 2);             // 0.26 MB
  float* rowp = (float*)alloc((size_t)4 * NN * 4);           // 128 KB
  float* colp = (float*)alloc((size_t)RB * NN * 4);          // 8 MB
  float* drow = (float*)alloc((size_t)NN * 4);
  float* dcol = (float*)alloc((size_t)NN * 4);
  float* P   = (float*)alloc((size_t)NN * NH * 4);           // 8.4 MB
  u16* B1t   = (u16*)alloc((size_t)NH * NN * 2);             // 4.2 MB
  float* Qp  = (float*)alloc((size_t)SPLITZ * NN * NH * 4);  // 33.6 MB (reused as Hp)
  float* Q1  = (float*)alloc((size_t)NN * NH * 4);           // 8.4 MB
  u16* B2t   = (u16*)alloc((size_t)NH * NN * 2);             // 4.2 MB
  u16* Hb    = (u16*)alloc((size_t)NN * NH * 2);             // 4.2 MB
  float* R   = (float*)alloc((size_t)NN * 2 * 4);
  float* B3  = (float*)alloc((size_t)NN * 2 * 4);
  float* S1  = (float*)alloc((size_t)NN * 2 * 4);
  float* B4  = (float*)alloc((size_t)NN * 2 * 4);
  float* Hp  = Qp;  // alias: Qp consumed by r2_k before gemm3 writes Hp

  conv_adj_k<<<dim3(4, RB), 256, 0, stream>>>(adj, adjb, rowp, colp);
  reduce_sums_k<<<NN / 256, 256, 0, stream>>>(rowp, colp, drow, dcol);
  convx_k<<<2048, 256, 0, stream>>>(x, xb);
  convw1_k<<<dim3(8, 16), 256, 0, stream>>>(W1, W1t);

  // P = x@W1 (fp32 out)
  gemm_k<<<dim3(2, 64, 1), 256, 0, stream>>>(xb, NF, W1t, NF, NF, P);
  t1_k<<<dim3(8, 256), 256, 0, stream>>>(P, dcol, B1t);

  // Qp[z] = partial adj@B1
  gemm_k<<<dim3(2, 64, SPLITZ), 256, 0, stream>>>(adjb, NN, B1t, NN, NN / SPLITZ, Qp);
  r2_k<<<dim3(8, 256), 256, 0, stream>>>(Qp, drow, dcol, Q1, B2t);

  // Hp[z] = partial adj@B2
  gemm_k<<<dim3(2, 64, SPLITZ), 256, 0, stream>>>(adjb, NN, B2t, NN, NN / SPLITZ, Hp);
  r3_k<<<2048, 256, 0, stream>>>(Hp, P, Q1, drow, Hb);

  r_k<<<NN / 4, 256, 0, stream>>>(Hb, W2, dcol, R, B3);
  gemv_k<<<NN, 256, 0, stream>>>(adjb, B3, drow, dcol, nullptr, nullptr, nullptr, S1, B4, nullptr, 0);
  gemv_k<<<NN, 256, 0, stream>>>(adjb, B4, drow, dcol, R, S1, b2, nullptr, nullptr, outp, 1);
}